// Round 1
// baseline (72.647 us; speedup 1.0000x reference)
//
#include <hip/hip_runtime.h>
#include <hip/hip_bf16.h>

typedef __attribute__((ext_vector_type(8))) short bf16x8;   // MFMA A/B frag (8 bf16)
typedef __attribute__((ext_vector_type(4))) float f32x4;    // MFMA C/D frag
typedef __attribute__((ext_vector_type(4))) short s16x4;

#define LDSS 72   // LDS row stride in bf16 elems (64 + 8 pad -> 144B rows, 16B aligned, <=2-way bank alias)

__device__ __forceinline__ short f2bf(float f) {
    union { float f; unsigned u; } v; v.f = f;
    unsigned r = v.u + 0x7fffu + ((v.u >> 16) & 1u);  // round-to-nearest-even
    return (short)(r >> 16);
}

// out[b,i,j] = ||x_i||^2 + ||y_j||^2 - 2 * dot(x_i, y_j)
// 128x128 tile per block; dot via bf16 MFMA 16x16x32 (K=64 in two MFMAs); norms fp32.
__global__ __launch_bounds__(256) void pdist_kernel(
    const float* __restrict__ x, const float* __restrict__ y,
    float* __restrict__ out, int n)
{
    constexpr int D = 64;
    __shared__ short xs[128 * LDSS];
    __shared__ short ys[128 * LDSS];
    __shared__ float xn[128];
    __shared__ float yn[128];

    const int b  = blockIdx.z;
    const int i0 = blockIdx.y * 128;
    const int j0 = blockIdx.x * 128;
    const float* xb = x + ((size_t)b * n + i0) * D;   // 128 x 64 tile, contiguous
    const float* yb = y + ((size_t)b * n + j0) * D;

    const int t = threadIdx.x;

    // ---- stage tiles to LDS as bf16 (each thread: 8 float4 chunks per matrix) ----
    const f32x4* xv = (const f32x4*)xb;
    const f32x4* yv = (const f32x4*)yb;
    #pragma unroll
    for (int c = 0; c < 8; ++c) {
        int idx  = t + c * 256;          // float4 index in 128x64 tile (2048 total)
        int row  = idx >> 4;             // 16 float4 per row
        int col4 = (idx & 15) << 2;
        f32x4 vx = xv[idx];
        f32x4 vy = yv[idx];
        s16x4 sx = { f2bf(vx.x), f2bf(vx.y), f2bf(vx.z), f2bf(vx.w) };
        s16x4 sy = { f2bf(vy.x), f2bf(vy.y), f2bf(vy.z), f2bf(vy.w) };
        *(s16x4*)&xs[row * LDSS + col4] = sx;
        *(s16x4*)&ys[row * LDSS + col4] = sy;
    }

    // ---- fp32 row norms from global (L2-hot) ----
    {
        int r = t & 127;
        const f32x4* p = (const f32x4*)((t < 128 ? xb : yb) + r * D);
        float s = 0.f;
        #pragma unroll
        for (int c = 0; c < 16; ++c) {
            f32x4 v = p[c];
            s += v.x * v.x + v.y * v.y + v.z * v.z + v.w * v.w;
        }
        if (t < 128) xn[r] = s; else yn[r] = s;
    }

    __syncthreads();

    // ---- MFMA compute: wave w owns 64x64 quadrant ----
    const int lane = t & 63;
    const int w    = t >> 6;
    const int wi   = (w >> 1) * 64;
    const int wj   = (w & 1)  * 64;
    const int lrow = lane & 15;
    const int quad = lane >> 4;

    const short* xbase = &xs[(wi + lrow) * LDSS + quad * 8];
    const short* ybase = &ys[(wj + lrow) * LDSS + quad * 8];

    bf16x8 af[4][2], bf[4][2];
    #pragma unroll
    for (int ti = 0; ti < 4; ++ti) {
        af[ti][0] = *(const bf16x8*)(xbase + ti * 16 * LDSS);
        af[ti][1] = *(const bf16x8*)(xbase + ti * 16 * LDSS + 32);
        bf[ti][0] = *(const bf16x8*)(ybase + ti * 16 * LDSS);
        bf[ti][1] = *(const bf16x8*)(ybase + ti * 16 * LDSS + 32);
    }

    f32x4 acc[4][4];
    #pragma unroll
    for (int ti = 0; ti < 4; ++ti)
        #pragma unroll
        for (int tj = 0; tj < 4; ++tj) {
            f32x4 z = {0.f, 0.f, 0.f, 0.f};
            z = __builtin_amdgcn_mfma_f32_16x16x32_bf16(af[ti][0], bf[tj][0], z, 0, 0, 0);
            z = __builtin_amdgcn_mfma_f32_16x16x32_bf16(af[ti][1], bf[tj][1], z, 0, 0, 0);
            acc[ti][tj] = z;
        }

    // ---- epilogue: out = xn + yn - 2*dot ----
    // C/D layout (16x16x32): col = lane&15, row = quad*4 + reg  [m89-verified]
    float* outb = out + (size_t)b * n * n;
    #pragma unroll
    for (int ti = 0; ti < 4; ++ti) {
        #pragma unroll
        for (int tj = 0; tj < 4; ++tj) {
            int gj   = j0 + wj + tj * 16 + lrow;
            float yv_ = yn[wj + tj * 16 + lrow];
            #pragma unroll
            for (int r = 0; r < 4; ++r) {
                int li = wi + ti * 16 + quad * 4 + r;
                int gi = i0 + li;
                float v = xn[li] + yv_ - 2.0f * acc[ti][tj][r];
                outb[(size_t)gi * n + gj] = v;
            }
        }
    }
}

extern "C" void kernel_launch(void* const* d_in, const int* in_sizes, int n_in,
                              void* d_out, int out_size, void* d_ws, size_t ws_size,
                              hipStream_t stream) {
    const float* x = (const float*)d_in[0];
    const float* y = (const float*)d_in[1];
    float* out = (float*)d_out;

    // in_sizes[0] = B*n*64, out_size = B*n*n  =>  n = out_size*64 / in_sizes[0]
    const long long n = ((long long)out_size * 64) / in_sizes[0];
    const long long B = (long long)in_sizes[0] / (n * 64);

    dim3 grid((unsigned)(n / 128), (unsigned)(n / 128), (unsigned)B);
    pdist_kernel<<<grid, 256, 0, stream>>>(x, y, out, (int)n);
}